// Round 7
// baseline (271.150 us; speedup 1.0000x reference)
//
#include <hip/hip_runtime.h>

#define N_    8192
#define T_    20
#define M_    6
#define D_    9
#define NM_   (N_*M_)        // 49152 LSTM chains
#define NT_   (N_*T_)        // 163840 GNN problems
#define NTM7_ (N_*T_*M_*7)   // 6881280 elements per output tensor

#define LOG2E 1.44269504088896f

typedef __attribute__((ext_vector_type(2))) float v2f;

// native-rate activations: v_exp_f32 + v_rcp_f32 (no IEEE div sequence)
__device__ __forceinline__ float sigm(float x){
    return __builtin_amdgcn_rcpf(1.f + __builtin_amdgcn_exp2f(-LOG2E * x));
}
__device__ __forceinline__ float tanh_(float x){
    return fmaf(2.f, __builtin_amdgcn_rcpf(1.f + __builtin_amdgcn_exp2f(-2.f*LOG2E * x)), -1.f);
}
__device__ __forceinline__ v2f splat(float s){ return (v2f){s, s}; }
__device__ __forceinline__ v2f sigm2(v2f x){ v2f r; r.x = sigm(x.x); r.y = sigm(x.y); return r; }
__device__ __forceinline__ v2f tanh2(v2f x){ v2f r; r.x = tanh_(x.x); r.y = tanh_(x.y); return r; }
__device__ __forceinline__ v2f relu2(v2f x){ v2f r; r.x = fmaxf(x.x,0.f); r.y = fmaxf(x.y,0.f); return r; }

// ---------------------------------------------------------------------------
// R15: R14's verified fused kernel (155 us, passing), repacked as FOUR fully
// independent waves per workgroup (wave w = n = blockIdx*4+w), each with a
// private LDS slice. NO barriers: every cross-lane handoff is same-wave
// through LDS, and DS ops from one wave execute in order (the barrier-free
// mbuf pattern verified since R8). Grid 8192 -> 2048 WGs.
// Purpose: test/defeat the apparent ~53 WG/us single-wave-workgroup dispatch
// ceiling that has pinned residency at ~7 waves/CU for three rounds.
// LDS/WG = 4 x 10672 = 42688 B -> 3 blocks/CU = 12 waves/CU ceiling.
// Per-wave code byte-identical to R14 => absmax unchanged.
// ---------------------------------------------------------------------------
__global__ __launch_bounds__(256) void k_fused(
    const float* __restrict__ nf,    // (N,T,M,3)
    const float* __restrict__ pos,   // (N,T,M,6)
    const float* __restrict__ am,    // (N,T,M,M)
    const float* __restrict__ msgW, const float* __restrict__ msgb,
    const float* __restrict__ gWih, const float* __restrict__ gWhh,
    const float* __restrict__ gbih, const float* __restrict__ gbhh,
    const float* __restrict__ ro1W, const float* __restrict__ ro1b,
    const float* __restrict__ ro2W, const float* __restrict__ ro2b,
    const float* __restrict__ fWih, const float* __restrict__ fWhh,
    const float* __restrict__ fbih, const float* __restrict__ fbhh,
    const float* __restrict__ bWih, const float* __restrict__ bWhh,
    const float* __restrict__ bbih, const float* __restrict__ bbhh,
    const float* __restrict__ lr1W, const float* __restrict__ lr1b,
    const float* __restrict__ lr2W, const float* __restrict__ lr2b,
    const int*   __restrict__ numrec,
    float* __restrict__ out,         // pred_label region
    float* __restrict__ out0)        // pred_label0 region
{
    __shared__ float  hx[4][T_ * 3 * D_ * 2];  // 4x4320 B: [t][pair][d][par]
    __shared__ float4 hxs4[4][7 * 11];         // 4x1232 B: [row][j] {hA,hB,xA,xB}
    __shared__ v2f    shpool[4][640];          // 4x5120 B: mbuf (ph1) / qsum (ph2/3)

    const int wv   = threadIdx.x >> 6;
    const int lane = threadIdx.x & 63;
    const int n    = blockIdx.x * 4 + wv;

    float*  hxw = hx[wv];
    float4* hx4 = hxs4[wv];
    v2f*    shp = shpool[wv];

    // ===================== PHASE 1: GNN =====================
    {
        const int g    = lane / 6;
        const int i    = lane - g * 6;
        const int gB   = g * 58;
        const bool lactive = (lane < 60);

        const int wbase = n * 20;
        const int ntA = lactive ? (wbase + g)      : wbase;
        const int ntB = lactive ? (wbase + 10 + g) : wbase;
        const int nA = ntA / T_, tA = ntA - nA * T_;
        const int nB = ntB / T_, tB = ntB - nB * T_;

        v2f s[D_];
        {
            const float* pA = nf + (size_t)ntA * 18 + i * 3;
            const float* pB = nf + (size_t)ntB * 18 + i * 3;
            #pragma unroll
            for (int k = 0; k < 3; ++k) { s[k].x = pA[k]; s[k].y = pB[k]; }
        }
        {
            const float2* pA = (const float2*)(pos + (size_t)ntA * 36 + i * 6);
            const float2* pB = (const float2*)(pos + (size_t)ntB * 36 + i * 6);
            #pragma unroll
            for (int k = 0; k < 3; ++k) {
                float2 a = pA[k], b = pB[k];
                s[3 + 2*k]     = (v2f){a.x, b.x};
                s[3 + 2*k + 1] = (v2f){a.y, b.y};
            }
        }
        v2f attr[M_];
        {
            const float2* pA = (const float2*)(am + (size_t)ntA * 36 + i * 6);
            const float2* pB = (const float2*)(am + (size_t)ntB * 36 + i * 6);
            #pragma unroll
            for (int k = 0; k < 3; ++k) {
                float2 a = pA[k], b = pB[k];
                attr[2*k]     = (v2f){a.x, b.x};
                attr[2*k + 1] = (v2f){a.y, b.y};
            }
        }
        const int nrA = numrec[nA * T_];
        const int nrB = numrec[nB * T_];
        #pragma unroll
        for (int q = 0; q < M_; ++q) {
            attr[q].x *= (q < nrA) ? 1.f : 0.f;
            attr[q].y *= (q < nrB) ? 1.f : 0.f;
        }
        v2f vmi; vmi.x = (i < nrA) ? 1.f : 0.f; vmi.y = (i < nrB) ? 1.f : 0.f;

        #pragma unroll
        for (int it = 0; it < 2; ++it) {
            #pragma unroll
            for (int d = 0; d < D_; ++d) {
                v2f a = splat(msgb[d]);
                #pragma unroll
                for (int k = 0; k < D_; ++k) a += s[k] * msgW[d*9 + k];
                shp[gB + d*6 + i] = a;              // mbuf region
            }
            v2f mm[D_];
            #pragma unroll
            for (int d = 0; d < D_; ++d) {
                const float4* rp = (const float4*)&shp[gB + d*6];
                float4 p0 = rp[0], p1 = rp[1], p2 = rp[2];
                v2f a = attr[0] * (v2f){p0.x, p0.y};
                a += attr[1] * (v2f){p0.z, p0.w};
                a += attr[2] * (v2f){p1.x, p1.y};
                a += attr[3] * (v2f){p1.z, p1.w};
                a += attr[4] * (v2f){p2.x, p2.y};
                a += attr[5] * (v2f){p2.z, p2.w};
                mm[d] = a;
            }
            v2f grz[18], gxn[9], ghn[9];
            #pragma unroll
            for (int j = 0; j < 18; ++j) {
                v2f a = splat(gbih[j] + gbhh[j]);
                #pragma unroll
                for (int k = 0; k < D_; ++k) {
                    a += mm[k] * gWih[j*9 + k];
                    a += s[k]  * gWhh[j*9 + k];
                }
                grz[j] = a;
            }
            #pragma unroll
            for (int j = 0; j < 9; ++j) {
                v2f ax = splat(gbih[18 + j]), ah = splat(gbhh[18 + j]);
                #pragma unroll
                for (int k = 0; k < D_; ++k) {
                    ax += mm[k] * gWih[(18 + j)*9 + k];
                    ah += s[k]  * gWhh[(18 + j)*9 + k];
                }
                gxn[j] = ax; ghn[j] = ah;
            }
            #pragma unroll
            for (int d = 0; d < D_; ++d) {
                v2f r  = sigm2(grz[d]);
                v2f z  = sigm2(grz[9 + d]);
                v2f nn = tanh2(gxn[d] + r * ghn[d]);
                s[d] = vmi * ((splat(1.f) - z) * nn + z * s[d]);
            }
        }

        // hid -> LDS hxw[t][pair][d][par]
        if (lactive) {
            const int pr = i >> 1, par = i & 1;
            #pragma unroll
            for (int d = 0; d < D_; ++d) {
                hxw[((tA*3 + pr)*9 + d)*2 + par] = s[d].x;
                hxw[((tB*3 + pr)*9 + d)*2 + par] = s[d].y;
            }
        }

        v2f q9[D_];
        #pragma unroll
        for (int d = 0; d < D_; ++d) {
            v2f a = splat(ro1b[d]);
            #pragma unroll
            for (int k = 0; k < D_; ++k) a += s[k] * ro1W[d*9 + k];
            q9[d] = relu2(a);
        }
        if (lactive) {
            float* opA = out0 + (size_t)ntA * 42 + i * 7;
            float* opB = out0 + (size_t)ntB * 42 + i * 7;
            #pragma unroll
            for (int j = 0; j < 7; ++j) {
                v2f a = splat(ro2b[j]);
                #pragma unroll
                for (int k = 0; k < D_; ++k) a += q9[k] * ro2W[j*9 + k];
                a *= vmi;
                opA[j] = a.x; opB[j] = a.y;
            }
        }
    }

    // no barrier: all cross-lane handoff is same-wave; DS ops execute in order

    // ===================== PHASE 2: biLSTM scans + fused lr1 =====================
    {
        int grpL = lane / 9;                   // 0..7
        if (grpL == 7) grpL = 6;               // lane 63 -> dummy row 6
        const int dd  = (lane == 63) ? 0 : (lane - grpL * 9);  // 0..8
        const bool sv   = (grpL < 6);          // real scan lane
        const int  p    = sv ? (grpL % 3) : 0; // pair 0..2
        const int  dir  = sv ? (grpL / 3) : 0; // 0 = fwd, 1 = bwd
        const int  xrow = grpL * 11;           // hxs4 row (0..6)

        const float* Wih = dir ? bWih : fWih;
        const float* Whh = dir ? bWhh : fWhh;
        const float* Bih = dir ? bbih : fbih;
        const float* Bhh = dir ? bbhh : fbhh;

        float wxi[9], wxf[9], wxg[9], wxo[9], whi[9], whf[9], whg[9], who[9];
        #pragma unroll
        for (int k = 0; k < 9; ++k) {
            wxi[k] = Wih[(dd     )*9 + k];  whi[k] = Whh[(dd     )*9 + k];
            wxf[k] = Wih[(9  + dd)*9 + k];  whf[k] = Whh[(9  + dd)*9 + k];
            wxg[k] = Wih[(18 + dd)*9 + k];  whg[k] = Whh[(18 + dd)*9 + k];
            wxo[k] = Wih[(27 + dd)*9 + k];  who[k] = Whh[(27 + dd)*9 + k];
        }
        const float bi = Bih[dd]      + Bhh[dd];
        const float bf = Bih[9 + dd]  + Bhh[9 + dd];
        const float bg = Bih[18 + dd] + Bhh[18 + dd];
        const float bo = Bih[27 + dd] + Bhh[27 + dd];

        // lr1 row for this lane's q-output: fwd -> cols 0..8, bwd -> cols 9..17
        float w1r[9];
        #pragma unroll
        for (int k = 0; k < 9; ++k) w1r[k] = lr1W[dd*18 + dir*9 + k];

        const int t0 = dir ? (T_ - 1) : 0;
        const int ts = dir ? -1 : 1;

        {
            v2f x0 = *(const v2f*)&hxw[((t0*3 + p)*9 + dd)*2];
            hx4[xrow + dd] = make_float4(0.f, 0.f, x0.x, x0.y);  // {h(-1), x(t0)}
        }
        v2f h = splat(0.f), c = splat(0.f);
        #pragma unroll 1
        for (int ss = 0; ss < T_; ++ss) {
            const int t = t0 + ts * ss;
            v2f xn = splat(0.f);
            if (ss < T_ - 1) xn = *(const v2f*)&hxw[(((t + ts)*3 + p)*9 + dd)*2];

            v2f gi = splat(bi), gf = splat(bf), gg = splat(bg), go = splat(bo);
            v2f qc = splat(0.f);
            #pragma unroll
            for (int j = 0; j < 9; ++j) {
                float4 v = hx4[xrow + j];                  // broadcast b128
                v2f hj = (v2f){v.x, v.y}, xj = (v2f){v.z, v.w};
                gi += hj * whi[j]; gi += xj * wxi[j];
                gf += hj * whf[j]; gf += xj * wxf[j];
                gg += hj * whg[j]; gg += xj * wxg[j];
                go += hj * who[j]; go += xj * wxo[j];
                qc += hj * w1r[j];                         // fused lr1 (h[ss-1])
            }

            // qsum write for t_prev (skip ss==0: h(-1)=0 row is not an output)
            if (ss > 0 && sv) {
                const int tq = dir ? (20 - ss) : (ss - 1);
                const int qa = (p*20 + tq)*10 + dd;
                if (ss <= 10) shp[qa] = qc;                // first writer
                else          shp[qa] += qc;               // second writer
            }

            c = sigm2(gf) * c + sigm2(gi) * tanh2(gg);
            h = sigm2(go) * tanh2(c);
            hx4[xrow + dd] = make_float4(h.x, h.y, xn.x, xn.y);  // {h_ss, x_next}
        }

        // epilogue: lr1 contribution of the final h (t = 19 fwd / 0 bwd)
        {
            v2f qc = splat(0.f);
            #pragma unroll
            for (int j = 0; j < 9; ++j) {
                float4 v = hx4[xrow + j];
                qc += (v2f){v.x, v.y} * w1r[j];
            }
            if (sv) {
                const int tq = dir ? 0 : 19;
                shp[(p*20 + tq)*10 + dd] += qc;            // always second writer
            }
        }
    }

    // no barrier: qsum producer/consumer are the same wave

    // ===================== PHASE 3: readout =====================
    // 60 items: (pair 0..2) x (t 0..19); each outputs BOTH chains of the pair.
    if (lane < 60) {
        const int pp = lane / 20;
        const int t  = lane - pp * 20;
        const v2f* qrow = &shp[(pp*20 + t)*10];

        v2f q[9];
        #pragma unroll
        for (int dd2 = 0; dd2 < 9; ++dd2)
            q[dd2] = relu2(qrow[dd2] + splat(lr1b[dd2]));

        const int mA2 = 2 * pp, mB2 = mA2 + 1;
        const int nr = numrec[n * T_];
        v2f vi;
        vi.x = (mA2 < nr) ? 1.f : 0.f;
        vi.y = (mB2 < nr) ? 1.f : 0.f;

        float* opA = out + (size_t)((n * T_ + t) * M_ + mA2) * 7;
        float* opB = out + (size_t)((n * T_ + t) * M_ + mB2) * 7;
        #pragma unroll
        for (int j = 0; j < 7; ++j) {
            v2f a = splat(lr2b[j]);
            #pragma unroll
            for (int k = 0; k < 9; ++k) a += q[k] * lr2W[j*9 + k];
            a *= vi;
            opA[j] = a.x; opB[j] = a.y;
        }
    }
}

extern "C" void kernel_launch(void* const* d_in, const int* in_sizes, int n_in,
                              void* d_out, int out_size, void* d_ws, size_t ws_size,
                              hipStream_t stream) {
    const float* nf    = (const float*)d_in[0];
    const float* pos   = (const float*)d_in[1];
    const float* am    = (const float*)d_in[2];
    const float* msgW  = (const float*)d_in[3];
    const float* msgb  = (const float*)d_in[4];
    const float* gWih  = (const float*)d_in[5];
    const float* gWhh  = (const float*)d_in[6];
    const float* gbih  = (const float*)d_in[7];
    const float* gbhh  = (const float*)d_in[8];
    const float* ro1W  = (const float*)d_in[9];
    const float* ro1b  = (const float*)d_in[10];
    const float* ro2W  = (const float*)d_in[11];
    const float* ro2b  = (const float*)d_in[12];
    const float* lfWih = (const float*)d_in[13];
    const float* lfWhh = (const float*)d_in[14];
    const float* lfbih = (const float*)d_in[15];
    const float* lfbhh = (const float*)d_in[16];
    const float* lbWih = (const float*)d_in[17];
    const float* lbWhh = (const float*)d_in[18];
    const float* lbbih = (const float*)d_in[19];
    const float* lbbhh = (const float*)d_in[20];
    const float* lr1W  = (const float*)d_in[21];
    const float* lr1b  = (const float*)d_in[22];
    const float* lr2W  = (const float*)d_in[23];
    const float* lr2b  = (const float*)d_in[24];
    const int* numrec  = (const int*)d_in[25];

    float* outp = (float*)d_out;           // pred_label
    float* out0 = (float*)d_out + NTM7_;   // pred_label0

    // 4 independent waves (4 n's) per workgroup -> 2048 WGs
    k_fused<<<N_ / 4, 256, 0, stream>>>(nf, pos, am, msgW, msgb, gWih, gWhh,
                                        gbih, gbhh, ro1W, ro1b, ro2W, ro2b,
                                        lfWih, lfWhh, lfbih, lfbhh,
                                        lbWih, lbWhh, lbbih, lbbhh,
                                        lr1W, lr1b, lr2W, lr2b, numrec,
                                        outp, out0);
}

// Round 8
// 266.362 us; speedup vs baseline: 1.0180x; 1.0180x over previous
//
#include <hip/hip_runtime.h>

#define N_    8192
#define T_    20
#define M_    6
#define D_    9
#define NM_   (N_*M_)        // 49152 LSTM chains
#define NT_   (N_*T_)        // 163840 GNN problems
#define NTM7_ (N_*T_*M_*7)   // 6881280 elements per output tensor

#define LOG2E 1.44269504088896f

typedef __attribute__((ext_vector_type(2))) float v2f;

// native-rate activations: v_exp_f32 + v_rcp_f32 (no IEEE div sequence)
__device__ __forceinline__ float sigm(float x){
    return __builtin_amdgcn_rcpf(1.f + __builtin_amdgcn_exp2f(-LOG2E * x));
}
__device__ __forceinline__ float tanh_(float x){
    return fmaf(2.f, __builtin_amdgcn_rcpf(1.f + __builtin_amdgcn_exp2f(-2.f*LOG2E * x)), -1.f);
}
__device__ __forceinline__ v2f splat(float s){ return (v2f){s, s}; }
__device__ __forceinline__ v2f sigm2(v2f x){ v2f r; r.x = sigm(x.x); r.y = sigm(x.y); return r; }
__device__ __forceinline__ v2f tanh2(v2f x){ v2f r; r.x = tanh_(x.x); r.y = tanh_(x.y); return r; }
__device__ __forceinline__ v2f relu2(v2f x){ v2f r; r.x = fmaxf(x.x,0.f); r.y = fmaxf(x.y,0.f); return r; }

// ---------------------------------------------------------------------------
// Packed-FP32 primitives. Hypothesis under test (R16): hipcc scalarizes v2f
// math into 2x v_fma_f32 (measured 30k issue-cyc/wave vs ~14k counted with
// packing assumed). v_pk_fma_f32 computes both halves in ONE instruction at
// full rate (CDNA2+). Semantics identical to the contracted fma the compiler
// already emits -> absmax unchanged.
// ---------------------------------------------------------------------------
__device__ __forceinline__ v2f pkfma(v2f a, v2f b, v2f acc){
    asm("v_pk_fma_f32 %0, %1, %2, %0" : "+v"(acc) : "v"(a), "v"(b));
    return acc;
}
__device__ __forceinline__ v2f pkmul(v2f a, v2f b){
    v2f d;
    asm("v_pk_mul_f32 %0, %1, %2" : "=v"(d) : "v"(a), "v"(b));
    return d;
}

// ---------------------------------------------------------------------------
// R16: R14 (verified 155 us) + forced v_pk_fma_f32 on the two hot loops whose
// operands are (or can cheaply become) natively v2f:
//   - phase-2 gate loop, h-side + qc: 45 sites/step. Weights whi/whf/whg/who/
//     w1r pre-splat to v2f pairs (+~90 VGPR, loop-invariant). x-side stays
//     scalar (another +45 pairs would hit the 256-VGPR spill cliff, R13).
//   - phase-1 mm loop: attr x mbuf, both already v2f, zero splat cost.
// Everything else byte-identical to R14.
// ---------------------------------------------------------------------------
__global__ __launch_bounds__(64) void k_fused(
    const float* __restrict__ nf,    // (N,T,M,3)
    const float* __restrict__ pos,   // (N,T,M,6)
    const float* __restrict__ am,    // (N,T,M,M)
    const float* __restrict__ msgW, const float* __restrict__ msgb,
    const float* __restrict__ gWih, const float* __restrict__ gWhh,
    const float* __restrict__ gbih, const float* __restrict__ gbhh,
    const float* __restrict__ ro1W, const float* __restrict__ ro1b,
    const float* __restrict__ ro2W, const float* __restrict__ ro2b,
    const float* __restrict__ fWih, const float* __restrict__ fWhh,
    const float* __restrict__ fbih, const float* __restrict__ fbhh,
    const float* __restrict__ bWih, const float* __restrict__ bWhh,
    const float* __restrict__ bbih, const float* __restrict__ bbhh,
    const float* __restrict__ lr1W, const float* __restrict__ lr1b,
    const float* __restrict__ lr2W, const float* __restrict__ lr2b,
    const int*   __restrict__ numrec,
    float* __restrict__ out,         // pred_label region
    float* __restrict__ out0)        // pred_label0 region
{
    __shared__ float  hx[T_ * 3 * D_ * 2];  // 4320 B: [t][pair][d][par]
    __shared__ float4 hxs4[7 * 11];         // 1232 B: [row][j] {hA,hB,xA,xB}; row 6 dummy
    __shared__ v2f    shpool[640];          // 5120 B: mbuf (ph1) / qsum[p][t][10] (ph2/3)

    const int lane = threadIdx.x & 63;
    const int n    = blockIdx.x;

    // ===================== PHASE 1: GNN =====================
    {
        const int g    = lane / 6;
        const int i    = lane - g * 6;
        const int gB   = g * 58;
        const bool lactive = (lane < 60);

        const int wbase = n * 20;
        const int ntA = lactive ? (wbase + g)      : wbase;
        const int ntB = lactive ? (wbase + 10 + g) : wbase;
        const int nA = ntA / T_, tA = ntA - nA * T_;
        const int nB = ntB / T_, tB = ntB - nB * T_;

        v2f s[D_];
        {
            const float* pA = nf + (size_t)ntA * 18 + i * 3;
            const float* pB = nf + (size_t)ntB * 18 + i * 3;
            #pragma unroll
            for (int k = 0; k < 3; ++k) { s[k].x = pA[k]; s[k].y = pB[k]; }
        }
        {
            const float2* pA = (const float2*)(pos + (size_t)ntA * 36 + i * 6);
            const float2* pB = (const float2*)(pos + (size_t)ntB * 36 + i * 6);
            #pragma unroll
            for (int k = 0; k < 3; ++k) {
                float2 a = pA[k], b = pB[k];
                s[3 + 2*k]     = (v2f){a.x, b.x};
                s[3 + 2*k + 1] = (v2f){a.y, b.y};
            }
        }
        v2f attr[M_];
        {
            const float2* pA = (const float2*)(am + (size_t)ntA * 36 + i * 6);
            const float2* pB = (const float2*)(am + (size_t)ntB * 36 + i * 6);
            #pragma unroll
            for (int k = 0; k < 3; ++k) {
                float2 a = pA[k], b = pB[k];
                attr[2*k]     = (v2f){a.x, b.x};
                attr[2*k + 1] = (v2f){a.y, b.y};
            }
        }
        const int nrA = numrec[nA * T_];
        const int nrB = numrec[nB * T_];
        #pragma unroll
        for (int q = 0; q < M_; ++q) {
            attr[q].x *= (q < nrA) ? 1.f : 0.f;
            attr[q].y *= (q < nrB) ? 1.f : 0.f;
        }
        v2f vmi; vmi.x = (i < nrA) ? 1.f : 0.f; vmi.y = (i < nrB) ? 1.f : 0.f;

        #pragma unroll
        for (int it = 0; it < 2; ++it) {
            #pragma unroll
            for (int d = 0; d < D_; ++d) {
                v2f a = splat(msgb[d]);
                #pragma unroll
                for (int k = 0; k < D_; ++k) a += s[k] * msgW[d*9 + k];
                shpool[gB + d*6 + i] = a;              // mbuf region
            }
            v2f mm[D_];
            #pragma unroll
            for (int d = 0; d < D_; ++d) {
                const float4* rp = (const float4*)&shpool[gB + d*6];
                float4 p0 = rp[0], p1 = rp[1], p2 = rp[2];
                v2f a = pkmul(attr[0], (v2f){p0.x, p0.y});
                a = pkfma(attr[1], (v2f){p0.z, p0.w}, a);
                a = pkfma(attr[2], (v2f){p1.x, p1.y}, a);
                a = pkfma(attr[3], (v2f){p1.z, p1.w}, a);
                a = pkfma(attr[4], (v2f){p2.x, p2.y}, a);
                a = pkfma(attr[5], (v2f){p2.z, p2.w}, a);
                mm[d] = a;
            }
            v2f grz[18], gxn[9], ghn[9];
            #pragma unroll
            for (int j = 0; j < 18; ++j) {
                v2f a = splat(gbih[j] + gbhh[j]);
                #pragma unroll
                for (int k = 0; k < D_; ++k) {
                    a += mm[k] * gWih[j*9 + k];
                    a += s[k]  * gWhh[j*9 + k];
                }
                grz[j] = a;
            }
            #pragma unroll
            for (int j = 0; j < 9; ++j) {
                v2f ax = splat(gbih[18 + j]), ah = splat(gbhh[18 + j]);
                #pragma unroll
                for (int k = 0; k < D_; ++k) {
                    ax += mm[k] * gWih[(18 + j)*9 + k];
                    ah += s[k]  * gWhh[(18 + j)*9 + k];
                }
                gxn[j] = ax; ghn[j] = ah;
            }
            #pragma unroll
            for (int d = 0; d < D_; ++d) {
                v2f r  = sigm2(grz[d]);
                v2f z  = sigm2(grz[9 + d]);
                v2f nn = tanh2(gxn[d] + r * ghn[d]);
                s[d] = vmi * ((splat(1.f) - z) * nn + z * s[d]);
            }
        }

        // hid -> LDS hx[t][pair][d][par]
        if (lactive) {
            const int pr = i >> 1, par = i & 1;
            #pragma unroll
            for (int d = 0; d < D_; ++d) {
                hx[((tA*3 + pr)*9 + d)*2 + par] = s[d].x;
                hx[((tB*3 + pr)*9 + d)*2 + par] = s[d].y;
            }
        }

        v2f q9[D_];
        #pragma unroll
        for (int d = 0; d < D_; ++d) {
            v2f a = splat(ro1b[d]);
            #pragma unroll
            for (int k = 0; k < D_; ++k) a += s[k] * ro1W[d*9 + k];
            q9[d] = relu2(a);
        }
        if (lactive) {
            float* opA = out0 + (size_t)ntA * 42 + i * 7;
            float* opB = out0 + (size_t)ntB * 42 + i * 7;
            #pragma unroll
            for (int j = 0; j < 7; ++j) {
                v2f a = splat(ro2b[j]);
                #pragma unroll
                for (int k = 0; k < D_; ++k) a += q9[k] * ro2W[j*9 + k];
                a *= vmi;
                opA[j] = a.x; opB[j] = a.y;
            }
        }
    }

    __syncthreads();   // orders hx / mbuf vs phase 2

    // ===================== PHASE 2: biLSTM scans + fused lr1 =====================
    {
        int grpL = lane / 9;                   // 0..7
        if (grpL == 7) grpL = 6;               // lane 63 -> dummy row 6
        const int dd  = (lane == 63) ? 0 : (lane - grpL * 9);  // 0..8
        const bool sv   = (grpL < 6);          // real scan lane
        const int  p    = sv ? (grpL % 3) : 0; // pair 0..2
        const int  dir  = sv ? (grpL / 3) : 0; // 0 = fwd, 1 = bwd
        const int  xrow = grpL * 11;           // hxs4 row (0..6)

        const float* Wih = dir ? bWih : fWih;
        const float* Whh = dir ? bWhh : fWhh;
        const float* Bih = dir ? bbih : fbih;
        const float* Bhh = dir ? bbhh : fbhh;

        // x-side weights stay scalar; h-side weights + w1r pre-splat to v2f
        // pairs (loop-invariant) so the gate h-FMAs and qc use v_pk_fma_f32.
        float wxi[9], wxf[9], wxg[9], wxo[9];
        v2f   whi[9], whf[9], whg[9], who[9], w1r[9];
        #pragma unroll
        for (int k = 0; k < 9; ++k) {
            wxi[k] = Wih[(dd     )*9 + k];  whi[k] = splat(Whh[(dd     )*9 + k]);
            wxf[k] = Wih[(9  + dd)*9 + k];  whf[k] = splat(Whh[(9  + dd)*9 + k]);
            wxg[k] = Wih[(18 + dd)*9 + k];  whg[k] = splat(Whh[(18 + dd)*9 + k]);
            wxo[k] = Wih[(27 + dd)*9 + k];  who[k] = splat(Whh[(27 + dd)*9 + k]);
            w1r[k] = splat(lr1W[dd*18 + dir*9 + k]);
        }
        const float bi = Bih[dd]      + Bhh[dd];
        const float bf = Bih[9 + dd]  + Bhh[9 + dd];
        const float bg = Bih[18 + dd] + Bhh[18 + dd];
        const float bo = Bih[27 + dd] + Bhh[27 + dd];

        const int t0 = dir ? (T_ - 1) : 0;
        const int ts = dir ? -1 : 1;

        {
            v2f x0 = *(const v2f*)&hx[((t0*3 + p)*9 + dd)*2];
            hxs4[xrow + dd] = make_float4(0.f, 0.f, x0.x, x0.y);  // {h(-1), x(t0)}
        }
        v2f h = splat(0.f), c = splat(0.f);
        #pragma unroll 1
        for (int ss = 0; ss < T_; ++ss) {
            const int t = t0 + ts * ss;
            v2f xn = splat(0.f);
            if (ss < T_ - 1) xn = *(const v2f*)&hx[(((t + ts)*3 + p)*9 + dd)*2];

            v2f gi = splat(bi), gf = splat(bf), gg = splat(bg), go = splat(bo);
            v2f qc = splat(0.f);
            #pragma unroll
            for (int j = 0; j < 9; ++j) {
                float4 v = hxs4[xrow + j];                 // broadcast b128
                v2f hj = (v2f){v.x, v.y}, xj = (v2f){v.z, v.w};
                gi = pkfma(hj, whi[j], gi);  gi += xj * wxi[j];
                gf = pkfma(hj, whf[j], gf);  gf += xj * wxf[j];
                gg = pkfma(hj, whg[j], gg);  gg += xj * wxg[j];
                go = pkfma(hj, who[j], go);  go += xj * wxo[j];
                qc = pkfma(hj, w1r[j], qc);                // fused lr1 (h[ss-1])
            }

            // qsum write for t_prev (skip ss==0: h(-1)=0 row is not an output)
            if (ss > 0 && sv) {
                const int tq = dir ? (20 - ss) : (ss - 1);
                const int qa = (p*20 + tq)*10 + dd;
                if (ss <= 10) shpool[qa] = qc;             // first writer
                else          shpool[qa] += qc;            // second writer
            }

            c = sigm2(gf) * c + sigm2(gi) * tanh2(gg);
            h = sigm2(go) * tanh2(c);
            hxs4[xrow + dd] = make_float4(h.x, h.y, xn.x, xn.y);  // {h_ss, x_next}
        }

        // epilogue: lr1 contribution of the final h (t = 19 fwd / 0 bwd)
        {
            v2f qc = splat(0.f);
            #pragma unroll
            for (int j = 0; j < 9; ++j) {
                float4 v = hxs4[xrow + j];
                qc = pkfma((v2f){v.x, v.y}, w1r[j], qc);
            }
            if (sv) {
                const int tq = dir ? 0 : 19;
                shpool[(p*20 + tq)*10 + dd] += qc;         // always second writer
            }
        }
    }

    __syncthreads();   // orders qsum writes vs phase-3 reads

    // ===================== PHASE 3: readout =====================
    // 60 items: (pair 0..2) x (t 0..19); each outputs BOTH chains of the pair.
    if (lane < 60) {
        const int pp = lane / 20;
        const int t  = lane - pp * 20;
        const v2f* qrow = &shpool[(pp*20 + t)*10];

        v2f q[9];
        #pragma unroll
        for (int dd2 = 0; dd2 < 9; ++dd2)
            q[dd2] = relu2(qrow[dd2] + splat(lr1b[dd2]));

        const int mA2 = 2 * pp, mB2 = mA2 + 1;
        const int nr = numrec[n * T_];
        v2f vi;
        vi.x = (mA2 < nr) ? 1.f : 0.f;
        vi.y = (mB2 < nr) ? 1.f : 0.f;

        float* opA = out + (size_t)((n * T_ + t) * M_ + mA2) * 7;
        float* opB = out + (size_t)((n * T_ + t) * M_ + mB2) * 7;
        #pragma unroll
        for (int j = 0; j < 7; ++j) {
            v2f a = splat(lr2b[j]);
            #pragma unroll
            for (int k = 0; k < 9; ++k) a += q[k] * lr2W[j*9 + k];
            a *= vi;
            opA[j] = a.x; opB[j] = a.y;
        }
    }
}

extern "C" void kernel_launch(void* const* d_in, const int* in_sizes, int n_in,
                              void* d_out, int out_size, void* d_ws, size_t ws_size,
                              hipStream_t stream) {
    const float* nf    = (const float*)d_in[0];
    const float* pos   = (const float*)d_in[1];
    const float* am    = (const float*)d_in[2];
    const float* msgW  = (const float*)d_in[3];
    const float* msgb  = (const float*)d_in[4];
    const float* gWih  = (const float*)d_in[5];
    const float* gWhh  = (const float*)d_in[6];
    const float* gbih  = (const float*)d_in[7];
    const float* gbhh  = (const float*)d_in[8];
    const float* ro1W  = (const float*)d_in[9];
    const float* ro1b  = (const float*)d_in[10];
    const float* ro2W  = (const float*)d_in[11];
    const float* ro2b  = (const float*)d_in[12];
    const float* lfWih = (const float*)d_in[13];
    const float* lfWhh = (const float*)d_in[14];
    const float* lfbih = (const float*)d_in[15];
    const float* lfbhh = (const float*)d_in[16];
    const float* lbWih = (const float*)d_in[17];
    const float* lbWhh = (const float*)d_in[18];
    const float* lbbih = (const float*)d_in[19];
    const float* lbbhh = (const float*)d_in[20];
    const float* lr1W  = (const float*)d_in[21];
    const float* lr1b  = (const float*)d_in[22];
    const float* lr2W  = (const float*)d_in[23];
    const float* lr2b  = (const float*)d_in[24];
    const int* numrec  = (const int*)d_in[25];

    float* outp = (float*)d_out;           // pred_label
    float* out0 = (float*)d_out + NTM7_;   // pred_label0

    // one wave per n -> 8192 single-wave blocks
    k_fused<<<N_, 64, 0, stream>>>(nf, pos, am, msgW, msgb, gWih, gWhh,
                                   gbih, gbhh, ro1W, ro1b, ro2W, ro2b,
                                   lfWih, lfWhh, lfbih, lfbhh,
                                   lbWih, lbWhh, lbbih, lbbhh,
                                   lr1W, lr1b, lr2W, lr2b, numrec,
                                   outp, out0);
}